// Round 15
// baseline (99.651 us; speedup 1.0000x reference)
//
#include <hip/hip_runtime.h>
#include <hip/hip_bf16.h>

#define BB   16
#define CIN  256
#define TN   4096
#define LOUT 4110
#define FTS  4224   // first_t per-batch stride (ints)

typedef __attribute__((ext_vector_type(8))) short s16x8;
typedef __attribute__((ext_vector_type(4))) float f32x4;

__device__ __forceinline__ float fsig(float g) {   // sigmoid w/ HW rcp (1 ulp)
  return __builtin_amdgcn_rcpf(1.f + __expf(-g));
}

// ---------------- workspace layout (bytes) ----------------
// featT  bf16 [B][T][256]        0          (33554432)
// wBpk   bf16 fragment-packed    33554432   (262144)  -> 33816576
// bnp    float4[256]             33816576   (4096)    -> 33820672
// wp0T   f32  [62][32]           33820672   (8192)    -> 33828864
// wp1M   bf16 frag-packed p1     33828864   (30720)   -> 33859584
// wp2M   bf16 frag-packed p2     33859584   (15360)   -> 33874944
// bnp0   float2[32]              33874944   (256)     -> 33875200
// bnp1   float2[32]              33875200   (256)     -> 33875456
// xx     f32  [B][T]             33890304
// wts    f32  [B][T]             34152448
// mvr    f32  [B][T]             34414592
// poses  f32  [B][T]             34676736
// firstT int  [B][4224]          34938880   (end 35209216)

// ======================= K0: weight prep =======================
__global__ __launch_bounds__(256) void k0_prep(
    const float* __restrict__ conv1_w, const float* __restrict__ p0_w,
    const float* __restrict__ p1_w, const float* __restrict__ p2_w,
    const float* __restrict__ bn1_g, const float* __restrict__ bn1_b,
    const float* __restrict__ bn1_m, const float* __restrict__ bn1_v,
    const float* __restrict__ p0_b, const float* __restrict__ p0g,
    const float* __restrict__ p0bb, const float* __restrict__ p0m,
    const float* __restrict__ p0v,
    const float* __restrict__ p1_b, const float* __restrict__ p1g,
    const float* __restrict__ p1bb, const float* __restrict__ p1m,
    const float* __restrict__ p1v,
    short* __restrict__ wBpk, float4* __restrict__ bnp,
    float* __restrict__ wp0T, short* __restrict__ wp1M,
    short* __restrict__ wp2M, float2* __restrict__ bnp0,
    float2* __restrict__ bnp1) {
  int bid = blockIdx.x, tid = threadIdx.x;
  if (bid < 512) {
    // wBpk flat: ((n16*8 + ks)*64 + l)*8 + i ; value = Wpacked[n16*16+(l&15)][ks*32+(l>>4)*8+i]
    int e = bid * 256 + tid;               // 0..131071
    int i = e & 7, l = (e >> 3) & 63, ks = (e >> 9) & 7, n16 = e >> 12;
    int n = n16 * 16 + (l & 15);           // packed col 0..511
    int j = n & 63;
    int co = (j < 32) ? ((n >> 6) * 32 + j) : (256 + (n >> 6) * 32 + (j - 32));
    int ci = ks * 32 + (l >> 4) * 8 + i;
    __hip_bfloat16 hv = __float2bfloat16(conv1_w[co * 256 + ci]);
    wBpk[e] = *(short*)&hv;
  } else {
    int idx = (bid - 512) * 256 + tid;     // 0..15359
    if (idx < 1984) {
      int ch = idx & 31, rem = idx >> 5;
      int ic = rem / 31, k = rem % 31;
      wp0T[idx] = p0_w[(ch * 2 + ic) * 31 + k];
    }
    {  // wp1M: idx bits [0:3)=i, [3:9)=l, [9)=nf, [10:..)=koff
      int i = idx & 7, l = (idx >> 3) & 63, nf = (idx >> 9) & 1, koff = idx >> 10;
      int ch = nf * 16 + (l & 15), ic = (l >> 4) * 8 + i;
      __hip_bfloat16 hv = __float2bfloat16(p1_w[(ch * 32 + ic) * 15 + koff]);
      wp1M[idx] = *(short*)&hv;
    }
    if (idx < 7680) {  // wp2M: bits [0:3)=i, [3:9)=l, [9:..)=koff
      int i = idx & 7, l = (idx >> 3) & 63, koff = idx >> 9;
      int n = l & 15, ic = (l >> 4) * 8 + i;
      float v = (n < 2) ? p2_w[(n * 32 + ic) * 15 + koff] : 0.f;
      __hip_bfloat16 hv = __float2bfloat16(v);
      wp2M[idx] = *(short*)&hv;
    }
    if (idx < 32) {
      int ch = idx;
      float sc = p0g[ch] * rsqrtf(p0v[ch] + 1e-5f);
      bnp0[ch] = make_float2(sc, (p0_b[ch] - p0m[ch]) * sc + p0bb[ch]);
    }
    if (idx >= 32 && idx < 64) {
      int ch = idx - 32;
      float sc = p1g[ch] * rsqrtf(p1v[ch] + 1e-5f);
      bnp1[ch] = make_float2(sc, (p1_b[ch] - p1m[ch]) * sc + p1bb[ch]);
    }
    if (idx < 256) {
      int c = idx;
      float sa = bn1_g[c] * rsqrtf(bn1_v[c] + 1e-3f);
      float ba = bn1_b[c] - bn1_m[c] * sa;
      float sg = bn1_g[c + 256] * rsqrtf(bn1_v[c + 256] + 1e-3f);
      float bg = bn1_b[c + 256] - bn1_m[c + 256] * sg;
      bnp[c] = make_float4(sa, ba, sg, bg);
    }
  }
}

// ========== K1 v9: single-barrier full-N block + fused staging (R14, frozen) ==========
__global__ __launch_bounds__(512, 4) void k1_mfma(
    const float* __restrict__ x, const float* __restrict__ w1x1,
    const short* __restrict__ wBpk, const float4* __restrict__ bnp,
    __hip_bfloat16* __restrict__ featT, float* __restrict__ xx) {
  int ty = blockIdx.x, b = blockIdx.y;
  int t0 = ty * 64;
  __shared__ __align__(16) unsigned int hb[64 * 132];
  __shared__ float xws[8][68];
  int tid = threadIdx.x;
  int l = tid & 63, wv = tid >> 6;
  int j = tid >> 4;                      // 0..31 (block-wide cpair sub)
  int tc = tid & 15;
  int q = (tc >> 1) & 3;
  const float* xb = x + (size_t)b * (CIN * TN) + t0 + 4 * tc;
  float xxp[4] = {0.f, 0.f, 0.f, 0.f};
#pragma unroll
  for (int iter = 0; iter < 4; ++iter) {
    int C = j + 32 * iter;               // cpair 0..127
    int ci = 2 * C;
    float4 f0 = *(const float4*)(xb + (size_t)ci * TN);
    float4 f1 = *(const float4*)(xb + (size_t)(ci + 1) * TN);
    float w0 = w1x1[ci], w1 = w1x1[ci + 1];
    unsigned int* dst = hb + (C ^ (q << 2));
    float fa[4] = {f0.x, f0.y, f0.z, f0.w};
    float fb[4] = {f1.x, f1.y, f1.z, f1.w};
#pragma unroll
    for (int r = 0; r < 4; ++r) {
      __hip_bfloat16 lo = __float2bfloat16(fa[r]);
      __hip_bfloat16 hi = __float2bfloat16(fb[r]);
      unsigned int pk = (unsigned int)(*(unsigned short*)&lo) |
                        ((unsigned int)(*(unsigned short*)&hi) << 16);
      dst[(4 * tc + r) * 132] = pk;
      xxp[r] = fmaf(w0, fa[r], fmaf(w1, fb[r], xxp[r]));
    }
  }
#pragma unroll
  for (int r = 0; r < 4; ++r) {          // reduce over same-tc lanes (stride 16)
    xxp[r] += __shfl_xor(xxp[r], 16);
    xxp[r] += __shfl_xor(xxp[r], 32);
  }
  if (l < 16) {
#pragma unroll
    for (int r = 0; r < 4; ++r) xws[wv][4 * l + r] = xxp[r];
  }
  __syncthreads();                       // hb + xws ready
  if (tid < 64)
    xx[b * TN + t0 + tid] = ((xws[0][tid] + xws[1][tid]) + (xws[2][tid] + xws[3][tid])) +
                            ((xws[4][tid] + xws[5][tid]) + (xws[6][tid] + xws[7][tid]));

  int lr = l & 15, lk = l >> 4;
  const short* wrow = wBpk + (size_t)l * 8;
  f32x4 acc[4][4];
#pragma unroll
  for (int i = 0; i < 4; ++i)
#pragma unroll
    for (int n = 0; n < 4; ++n) acc[i][n] = (f32x4){0.f, 0.f, 0.f, 0.f};

#pragma unroll 2
  for (int ks = 0; ks < 8; ++ks) {
    s16x8 bf[4], af[4];
#pragma unroll
    for (int nf = 0; nf < 4; ++nf)
      bf[nf] = *(const s16x8*)(wrow + (size_t)(wv * 4 + nf) * 4096 + ks * 512);
#pragma unroll
    for (int mf = 0; mf < 4; ++mf) {
      int row = mf * 16 + lr;
      int grp = ks * 4 + lk;
      int qr = (row >> 3) & 3;
      af[mf] = *(const s16x8*)(hb + row * 132 + ((grp ^ qr) << 2));
    }
#pragma unroll
    for (int mf = 0; mf < 4; ++mf)
#pragma unroll
      for (int nf = 0; nf < 4; ++nf)
        acc[mf][nf] = __builtin_amdgcn_mfma_f32_16x16x32_bf16(
            af[mf], bf[nf], acc[mf][nf], 0, 0, 0);
  }

  // epilogue: BN + GLU (packed col j pairs with j+32 -> frag nf vs nf+2, same lane)
  int cb = wv * 32;
#pragma unroll
  for (int nf = 0; nf < 2; ++nf) {
    float4 bn = bnp[cb + nf * 16 + lr];
    int c = cb + nf * 16 + lr;
#pragma unroll
    for (int mf = 0; mf < 4; ++mf) {
#pragma unroll
      for (int r = 0; r < 4; ++r) {
        float a = acc[mf][nf][r], g = acc[mf][nf + 2][r];
        float av = fmaf(a, bn.x, bn.y);
        float gv = fmaf(g, bn.z, bn.w);
        float fv = av * fsig(gv);
        int t = t0 + mf * 16 + lk * 4 + r;
        featT[((size_t)b * TN + t) * 256 + c] = __float2bfloat16(fv);
      }
    }
  }
}

// ========== K2 v3: 64-t tiles, 256 thr, grid 1024 (4 blocks/CU) ==========
// t out in [t0, t0+64). xin q<122 (t0-29..t0+93); h0T 96 rows (92 valid,
// i <-> t = t0-14+i); h1T 80 rows (78 valid, j <-> t = t0-7+j).
// p1: 5 m-frags over 4 waves (wave0 gets frags {0,4}); p2: frag wv exactly.
__global__ __launch_bounds__(256) void k2_pred(
    const float* __restrict__ xx,
    const float* __restrict__ wp0T, const float2* __restrict__ bnp0,
    const short* __restrict__ wp1M, const float2* __restrict__ bnp1,
    const short* __restrict__ wp2M, const float* __restrict__ p2_b,
    const float* __restrict__ norm_mean,
    float* __restrict__ wts, float* __restrict__ mvr) {
  int t0 = blockIdx.x * 64;
  int b = blockIdx.y;
  __shared__ float xin[2][128];     // q<122 valid, rest 0
  __shared__ short h0T[96 * 40];
  __shared__ short h1T[80 * 40];
  int tid = threadIdx.x;
  for (int q = tid; q < 128; q += 256) {
    int t = t0 - 29 + q;
    float v = (q < 122 && t >= 0 && t < TN) ? xx[b * TN + t] : 0.f;
    xin[0][q] = v;
    xin[1][q] = v * v;
  }
  if (tid < 128) h0T[(92 + (tid >> 5)) * 40 + (tid & 31)] = 0;      // pad rows 92..95
  if (tid >= 128 && tid < 192) {
    int z = tid - 128;
    h1T[(78 + (z >> 5)) * 40 + (z & 31)] = 0;                        // pad rows 78..79
  }
  __syncthreads();
  {  // p0: K=31, 2 in-ch, f32 VALU; thread (ch, tq 0..7) -> 12 outputs
    int ch = tid & 31, tq = tid >> 5;
    int i0 = tq * 12;                  // 0..84
    float2 bb0 = bnp0[ch];
    float a0[12];
#pragma unroll
    for (int j = 0; j < 12; ++j) a0[j] = 0.f;
#pragma unroll
    for (int ic = 0; ic < 2; ++ic) {
      float rr[44];
#pragma unroll
      for (int q = 0; q < 11; ++q) {
        float4 t4 = *(const float4*)(&xin[ic][i0 + q * 4]);
        rr[q * 4 + 0] = t4.x; rr[q * 4 + 1] = t4.y;
        rr[q * 4 + 2] = t4.z; rr[q * 4 + 3] = t4.w;
      }
#pragma unroll
      for (int k = 0; k < 31; ++k) {
        float w = wp0T[(ic * 31 + k) * 32 + ch];
#pragma unroll
        for (int j = 0; j < 12; ++j) a0[j] = fmaf(w, rr[j + k], a0[j]);
      }
    }
#pragma unroll
    for (int j = 0; j < 12; ++j) {
      int i = i0 + j;
      if (i < 92) {
        float v = a0[j] * bb0.x + bb0.y;
        float h = v * fsig(v);
        __hip_bfloat16 hv = __float2bfloat16(h);
        h0T[i * 40 + ch] = *(short*)&hv;
      }
    }
  }
  __syncthreads();
  int l = tid & 63, wv = tid >> 6;
  int lrow = l & 15, lk8 = (l >> 4) * 8;
  {  // p1: 15 shifted MFMAs (K=32=ic); 5 m-frags over 4 waves (wave0: {wv,4})
    f32x4 acc[2][2];
#pragma unroll
    for (int i = 0; i < 2; ++i)
#pragma unroll
      for (int j = 0; j < 2; ++j) acc[i][j] = (f32x4){0.f, 0.f, 0.f, 0.f};
    int nmf = (wv == 0) ? 2 : 1;
    for (int koff = 0; koff < 15; ++koff) {
      const short* bp = wp1M + koff * 1024;
      s16x8 bf0 = *(const s16x8*)(bp + l * 8);
      s16x8 bf1 = *(const s16x8*)(bp + 512 + l * 8);
      for (int mi = 0; mi < nmf; ++mi) {
        int mf = (mi == 0) ? wv : 4;
        s16x8 af = *(const s16x8*)(&h0T[(mf * 16 + koff + lrow) * 40 + lk8]);
        acc[mi][0] = __builtin_amdgcn_mfma_f32_16x16x32_bf16(af, bf0, acc[mi][0], 0, 0, 0);
        acc[mi][1] = __builtin_amdgcn_mfma_f32_16x16x32_bf16(af, bf1, acc[mi][1], 0, 0, 0);
      }
    }
    for (int mi = 0; mi < nmf; ++mi) {
      int mf = (mi == 0) ? wv : 4;
#pragma unroll
      for (int nf = 0; nf < 2; ++nf) {
        int ch = nf * 16 + lrow;
        float2 bb = bnp1[ch];
#pragma unroll
        for (int r = 0; r < 4; ++r) {
          int row = mf * 16 + (l >> 4) * 4 + r;
          if (row < 78) {
            float v = acc[mi][nf][r] * bb.x + bb.y;
            float h = v * fsig(v);
            __hip_bfloat16 hv = __float2bfloat16(h);
            h1T[row * 40 + ch] = *(short*)&hv;
          }
        }
      }
    }
  }
  __syncthreads();
  {  // p2: 15 shifted MFMAs, N=16 (2 cols used); 4 m-frags = 1/wave
    f32x4 acc2 = (f32x4){0.f, 0.f, 0.f, 0.f};
    for (int koff = 0; koff < 15; ++koff) {
      s16x8 bf = *(const s16x8*)(wp2M + koff * 512 + l * 8);
      s16x8 af = *(const s16x8*)(&h1T[(wv * 16 + koff + lrow) * 40 + lk8]);
      acc2 = __builtin_amdgcn_mfma_f32_16x16x32_bf16(af, bf, acc2, 0, 0, 0);
    }
    int ch = lrow;
    if (ch < 2) {
      float pb = p2_b[ch];
      float nm = norm_mean[0];
#pragma unroll
      for (int r = 0; r < 4; ++r) {
        int t = t0 + wv * 16 + (l >> 4) * 4 + r;
        float a = acc2[r] + pb;
        float s = fsig(a);
        if (ch == 0) wts[b * TN + t] = s;
        else         mvr[b * TN + t] = s * nm;
      }
    }
  }
}

// ========== K3 v2: coalesced LDS bounce + per-wave shfl scan (3 barriers) ==========
__global__ __launch_bounds__(256) void k3_scan(const float* __restrict__ mvr,
                                               float* __restrict__ poses,
                                               int* __restrict__ firstT) {
  int b = blockIdx.x, tid = threadIdx.x;
  __shared__ float stage[4096];
  __shared__ float wsum[4];
  __shared__ int shlast;
  for (int i = tid; i < 4096; i += 256) stage[i] = mvr[b * TN + i];  // coalesced
  __syncthreads();
  float v[16];
  float run = 0.f;
#pragma unroll
  for (int j = 0; j < 16; ++j) { run += stage[tid * 16 + j]; v[j] = run; }
  int l = tid & 63, wv = tid >> 6;
  float s = run;
#pragma unroll
  for (int off = 1; off < 64; off <<= 1) {   // wave inclusive scan
    float t = __shfl_up(s, off);
    if (l >= off) s += t;
  }
  if (l == 63) wsum[wv] = s;
  __syncthreads();
  float wpre = 0.f;
  for (int w2 = 0; w2 < wv; ++w2) wpre += wsum[w2];
  float incl = wpre + s;
  float total = wsum[0] + wsum[1] + wsum[2] + wsum[3];
  float excl = incl - run;
  float rn = total * (1.0f / 4096.0f);
  float inv = (rn > 1.0f) ? 1.0f / rn : 1.0f;
  float p16[16];
  float* pd = poses + b * TN + tid * 16;
#pragma unroll
  for (int j = 0; j < 16; ++j) { p16[j] = (excl + v[j]) * inv; pd[j] = p16[j]; }
  stage[tid] = p16[15];                      // boundary pose (bit-exact w/ stored)
  __syncthreads();
  int* ft = firstT + b * FTS;
  int prevf = (tid == 0) ? -1 : min((int)floorf(stage[tid - 1]), 4220);
  int f = prevf;
#pragma unroll
  for (int j = 0; j < 16; ++j) {
    f = min((int)floorf(p16[j]), 4220);
    for (int li = prevf + 1; li <= f; ++li) ft[li] = tid * 16 + j;
    prevf = f;
  }
  if (tid == 255) shlast = f;
  __syncthreads();
  for (int li = shlast + 1 + tid; li < FTS; li += 256) ft[li] = TN;
}

// ========== K4: gather pool v3 — register running-sums, 16-row tiles ==========
__global__ __launch_bounds__(256) void k4_gather(
    const __hip_bfloat16* __restrict__ featT, const float* __restrict__ wts,
    const float* __restrict__ poses, const int* __restrict__ firstT,
    float* __restrict__ out) {
  int d = blockIdx.x + 257 * blockIdx.y;         // 0..4111
  int w = (d & 7) * 514 + (d >> 3);              // XCD k owns b in [2k,2k+2), all lx
  int lx = w % 257, b = w / 257;
  int l0 = lx * 16;
  __shared__ float acc[16][259];
  int tid = threadIdx.x;
  for (int i = tid; i < 16 * 259; i += 256) ((float*)acc)[i] = 0.f;
  const int* ft = firstT + b * FTS;
  int ts = (l0 == 0) ? 0 : ft[l0 - 1];
  int te = ft[l0 + 16];
  __syncthreads();
  int c = tid;
  if (ts < te) {
    const float* pp = poses + b * TN;
    const float* wp = wts + b * TN;
    const __hip_bfloat16* fp = featT + (size_t)(b * TN) * 256 + c;
    float p_cur = pp[ts];
    float w_cur = wp[ts];
    float f_cur = __bfloat162float(fp[(size_t)ts * 256]);
    float S_lo = 0.f, S_hi = 0.f;
    int cur = (int)floorf(p_cur);
    for (int t = ts; t < te; ++t) {
      float p_nxt = 0.f, w_nxt = 0.f, f_nxt = 0.f;
      if (t + 1 < te) {                          // prefetch next iter
        p_nxt = pp[t + 1];
        w_nxt = wp[t + 1];
        f_nxt = __bfloat162float(fp[(size_t)(t + 1) * 256]);
      }
      int fi = (int)floorf(p_cur);
      if (fi < cur) fi = cur;                    // FP scan-boundary wobble guard
      if (fi != cur) {                           // wave-uniform advance
        int r = cur - l0;
        if (r >= 0 && r < 16) acc[r][c] = S_lo;  // row cur is final
        if (fi == cur + 1) {
          S_lo = S_hi;
        } else {                                 // jump (FP anomaly / init only)
          int r2 = cur + 1 - l0;
          if (r2 >= 0 && r2 < 16) acc[r2][c] = S_hi;
          S_lo = 0.f;
        }
        S_hi = 0.f;
        cur = fi;
      }
      float w2 = p_cur - (float)fi;
      float fw = f_cur * w_cur;
      S_lo = fmaf(1.f - w2, fw, S_lo);
      S_hi = fmaf(w2, fw, S_hi);
      p_cur = p_nxt; w_cur = w_nxt; f_cur = f_nxt;
    }
    int r = cur - l0;                            // final rows
    if (r >= 0 && r < 16) acc[r][c] = S_lo;
    int r2 = cur + 1 - l0;
    if (r2 >= 0 && r2 < 16) acc[r2][c] = S_hi;
  }
  __syncthreads();
  // dump: 16 consecutive lanes cover 16 l of one c-row -> coalesced 64B segments
  for (int i = tid; i < 4096; i += 256) {
    int c2 = i >> 4, r = i & 15;
    int l = l0 + r;
    if (l < LOUT) out[((size_t)b * 256 + c2) * LOUT + l] = acc[r][c2];
  }
}

// ======================= launch =======================
extern "C" void kernel_launch(void* const* d_in, const int* in_sizes, int n_in,
                              void* d_out, int out_size, void* d_ws, size_t ws_size,
                              hipStream_t stream) {
  const float* x       = (const float*)d_in[0];
  const float* conv1_w = (const float*)d_in[1];
  const float* bn1_g   = (const float*)d_in[2];
  const float* bn1_b   = (const float*)d_in[3];
  const float* bn1_m   = (const float*)d_in[4];
  const float* bn1_v   = (const float*)d_in[5];
  const float* w1x1    = (const float*)d_in[6];
  const float* p0_w    = (const float*)d_in[7];
  const float* p0_b    = (const float*)d_in[8];
  const float* p0g     = (const float*)d_in[9];
  const float* p0bb    = (const float*)d_in[10];
  const float* p0m     = (const float*)d_in[11];
  const float* p0v     = (const float*)d_in[12];
  const float* p1_w    = (const float*)d_in[13];
  const float* p1_b    = (const float*)d_in[14];
  const float* p1g     = (const float*)d_in[15];
  const float* p1bb    = (const float*)d_in[16];
  const float* p1m     = (const float*)d_in[17];
  const float* p1v     = (const float*)d_in[18];
  const float* p2_w    = (const float*)d_in[19];
  const float* p2_b    = (const float*)d_in[20];
  const float* nmean   = (const float*)d_in[21];

  char* ws = (char*)d_ws;
  __hip_bfloat16* featT = (__hip_bfloat16*)ws;
  short* wBpk   = (short*)(ws + 33554432);
  float4* bnp   = (float4*)(ws + 33816576);
  float* wp0T   = (float*)(ws + 33820672);
  short* wp1M   = (short*)(ws + 33828864);
  short* wp2M   = (short*)(ws + 33859584);
  float2* bnp0  = (float2*)(ws + 33874944);
  float2* bnp1  = (float2*)(ws + 33875200);
  float* xx     = (float*)(ws + 33890304);
  float* wts    = (float*)(ws + 34152448);
  float* mvr    = (float*)(ws + 34414592);
  float* poses  = (float*)(ws + 34676736);
  int*   firstT = (int*)  (ws + 34938880);
  float* out    = (float*)d_out;

  k0_prep<<<dim3(572), dim3(256), 0, stream>>>(
      conv1_w, p0_w, p1_w, p2_w, bn1_g, bn1_b, bn1_m, bn1_v,
      p0_b, p0g, p0bb, p0m, p0v, p1_b, p1g, p1bb, p1m, p1v,
      wBpk, bnp, wp0T, wp1M, wp2M, bnp0, bnp1);
  k1_mfma<<<dim3(64, 16), dim3(512), 0, stream>>>(x, w1x1, wBpk, bnp, featT, xx);
  k2_pred<<<dim3(64, 16), dim3(256), 0, stream>>>(xx, wp0T, bnp0, wp1M, bnp1,
                                                  wp2M, p2_b, nmean, wts, mvr);
  k3_scan<<<dim3(16), dim3(256), 0, stream>>>(mvr, poses, firstT);
  k4_gather<<<dim3(257, 16), dim3(256), 0, stream>>>(featT, wts, poses, firstT, out);
}

// Round 16
// 93.249 us; speedup vs baseline: 1.0686x; 1.0686x over previous
//
#include <hip/hip_runtime.h>
#include <hip/hip_bf16.h>

#define BB   16
#define CIN  256
#define TN   4096
#define LOUT 4110
#define FTS  4224   // first_t per-batch stride (ints)

typedef __attribute__((ext_vector_type(8))) short s16x8;
typedef __attribute__((ext_vector_type(4))) float f32x4;

__device__ __forceinline__ float fsig(float g) {   // sigmoid w/ HW rcp (1 ulp)
  return __builtin_amdgcn_rcpf(1.f + __expf(-g));
}

// ---------------- workspace layout (bytes) ----------------
// featT  bf16 [B][T][256]        0          (33554432)
// wBpk   bf16 fragment-packed    33554432   (262144)  -> 33816576
// bnp    float4[256]             33816576   (4096)    -> 33820672
// wp0T   f32  [62][32]           33820672   (8192)    -> 33828864
// wp1M   bf16 frag-packed p1     33828864   (30720)   -> 33859584
// wp2M   bf16 frag-packed p2     33859584   (15360)   -> 33874944
// bnp0   float2[32]              33874944   (256)     -> 33875200
// bnp1   float2[32]              33875200   (256)     -> 33875456
// xx     f32  [B][T]             33890304
// wts    f32  [B][T]             34152448
// mvr    f32  [B][T]             34414592
// poses  f32  [B][T]             34676736
// firstT int  [B][4224]          34938880   (end 35209216)

// ======================= K0: weight prep =======================
__global__ __launch_bounds__(256) void k0_prep(
    const float* __restrict__ conv1_w, const float* __restrict__ p0_w,
    const float* __restrict__ p1_w, const float* __restrict__ p2_w,
    const float* __restrict__ bn1_g, const float* __restrict__ bn1_b,
    const float* __restrict__ bn1_m, const float* __restrict__ bn1_v,
    const float* __restrict__ p0_b, const float* __restrict__ p0g,
    const float* __restrict__ p0bb, const float* __restrict__ p0m,
    const float* __restrict__ p0v,
    const float* __restrict__ p1_b, const float* __restrict__ p1g,
    const float* __restrict__ p1bb, const float* __restrict__ p1m,
    const float* __restrict__ p1v,
    short* __restrict__ wBpk, float4* __restrict__ bnp,
    float* __restrict__ wp0T, short* __restrict__ wp1M,
    short* __restrict__ wp2M, float2* __restrict__ bnp0,
    float2* __restrict__ bnp1) {
  int bid = blockIdx.x, tid = threadIdx.x;
  if (bid < 512) {
    // wBpk flat: ((n16*8 + ks)*64 + l)*8 + i ; value = Wpacked[n16*16+(l&15)][ks*32+(l>>4)*8+i]
    int e = bid * 256 + tid;               // 0..131071
    int i = e & 7, l = (e >> 3) & 63, ks = (e >> 9) & 7, n16 = e >> 12;
    int n = n16 * 16 + (l & 15);           // packed col 0..511
    int j = n & 63;
    int co = (j < 32) ? ((n >> 6) * 32 + j) : (256 + (n >> 6) * 32 + (j - 32));
    int ci = ks * 32 + (l >> 4) * 8 + i;
    __hip_bfloat16 hv = __float2bfloat16(conv1_w[co * 256 + ci]);
    wBpk[e] = *(short*)&hv;
  } else {
    int idx = (bid - 512) * 256 + tid;     // 0..15359
    if (idx < 1984) {
      int ch = idx & 31, rem = idx >> 5;
      int ic = rem / 31, k = rem % 31;
      wp0T[idx] = p0_w[(ch * 2 + ic) * 31 + k];
    }
    {  // wp1M: idx bits [0:3)=i, [3:9)=l, [9)=nf, [10:..)=koff
      int i = idx & 7, l = (idx >> 3) & 63, nf = (idx >> 9) & 1, koff = idx >> 10;
      int ch = nf * 16 + (l & 15), ic = (l >> 4) * 8 + i;
      __hip_bfloat16 hv = __float2bfloat16(p1_w[(ch * 32 + ic) * 15 + koff]);
      wp1M[idx] = *(short*)&hv;
    }
    if (idx < 7680) {  // wp2M: bits [0:3)=i, [3:9)=l, [9:..)=koff
      int i = idx & 7, l = (idx >> 3) & 63, koff = idx >> 9;
      int n = l & 15, ic = (l >> 4) * 8 + i;
      float v = (n < 2) ? p2_w[(n * 32 + ic) * 15 + koff] : 0.f;
      __hip_bfloat16 hv = __float2bfloat16(v);
      wp2M[idx] = *(short*)&hv;
    }
    if (idx < 32) {
      int ch = idx;
      float sc = p0g[ch] * rsqrtf(p0v[ch] + 1e-5f);
      bnp0[ch] = make_float2(sc, (p0_b[ch] - p0m[ch]) * sc + p0bb[ch]);
    }
    if (idx >= 32 && idx < 64) {
      int ch = idx - 32;
      float sc = p1g[ch] * rsqrtf(p1v[ch] + 1e-5f);
      bnp1[ch] = make_float2(sc, (p1_b[ch] - p1m[ch]) * sc + p1bb[ch]);
    }
    if (idx < 256) {
      int c = idx;
      float sa = bn1_g[c] * rsqrtf(bn1_v[c] + 1e-3f);
      float ba = bn1_b[c] - bn1_m[c] * sa;
      float sg = bn1_g[c + 256] * rsqrtf(bn1_v[c + 256] + 1e-3f);
      float bg = bn1_b[c + 256] - bn1_m[c + 256] * sg;
      bnp[c] = make_float4(sa, ba, sg, bg);
    }
  }
}

// ========== K1 v10: 32t x 512n single-barrier blocks, grid 2048 ==========
// ty 0..127, t0 = ty*32. 512 thr = 8 waves; wave wv owns GLU 64-col block wv.
// acc[2][4] = 32 AGPR (vs v9's 64) -> ~92 combined regs, 4 waves/SIMD at
// (512,4); 2048 blocks (8/CU queued) halve each block's serial staging chain.
// Staging: j=tid>>3 (cpair sub), tc=tid&7 (t-quad); 2 iters. Swizzle write
// q=(tc>>1)&3 == read qr=(row>>3)&3 for rows 0..31 (v9 algebra).
__global__ __launch_bounds__(512, 4) void k1_mfma(
    const float* __restrict__ x, const float* __restrict__ w1x1,
    const short* __restrict__ wBpk, const float4* __restrict__ bnp,
    __hip_bfloat16* __restrict__ featT, float* __restrict__ xx) {
  int ty = blockIdx.x, b = blockIdx.y;
  int t0 = ty * 32;
  __shared__ __align__(16) unsigned int hb[32 * 132];
  __shared__ float xws[8][36];
  int tid = threadIdx.x;
  int l = tid & 63, wv = tid >> 6;
  int j = tid >> 3;                      // 0..63 (block-wide cpair sub)
  int tc = tid & 7;                      // t-quad 0..7
  int q = (tc >> 1) & 3;
  const float* xb = x + (size_t)b * (CIN * TN) + t0 + 4 * tc;
  float xxp[4] = {0.f, 0.f, 0.f, 0.f};
#pragma unroll
  for (int iter = 0; iter < 2; ++iter) {
    int C = j + 64 * iter;               // cpair 0..127
    int ci = 2 * C;
    float4 f0 = *(const float4*)(xb + (size_t)ci * TN);
    float4 f1 = *(const float4*)(xb + (size_t)(ci + 1) * TN);
    float w0 = w1x1[ci], w1 = w1x1[ci + 1];
    unsigned int* dst = hb + (C ^ (q << 2));
    float fa[4] = {f0.x, f0.y, f0.z, f0.w};
    float fb[4] = {f1.x, f1.y, f1.z, f1.w};
#pragma unroll
    for (int r = 0; r < 4; ++r) {
      __hip_bfloat16 lo = __float2bfloat16(fa[r]);
      __hip_bfloat16 hi = __float2bfloat16(fb[r]);
      unsigned int pk = (unsigned int)(*(unsigned short*)&lo) |
                        ((unsigned int)(*(unsigned short*)&hi) << 16);
      dst[(4 * tc + r) * 132] = pk;
      xxp[r] = fmaf(w0, fa[r], fmaf(w1, fb[r], xxp[r]));
    }
  }
#pragma unroll
  for (int r = 0; r < 4; ++r) {          // reduce over same-tc lanes (stride 8)
    xxp[r] += __shfl_xor(xxp[r], 8);
    xxp[r] += __shfl_xor(xxp[r], 16);
    xxp[r] += __shfl_xor(xxp[r], 32);
  }
  if (l < 8) {
#pragma unroll
    for (int r = 0; r < 4; ++r) xws[wv][4 * l + r] = xxp[r];
  }
  __syncthreads();                       // hb + xws ready
  if (tid < 32)
    xx[b * TN + t0 + tid] = ((xws[0][tid] + xws[1][tid]) + (xws[2][tid] + xws[3][tid])) +
                            ((xws[4][tid] + xws[5][tid]) + (xws[6][tid] + xws[7][tid]));

  int lr = l & 15, lk = l >> 4;
  const short* wrow = wBpk + (size_t)l * 8;
  f32x4 acc[2][4];
#pragma unroll
  for (int i = 0; i < 2; ++i)
#pragma unroll
    for (int n = 0; n < 4; ++n) acc[i][n] = (f32x4){0.f, 0.f, 0.f, 0.f};

#pragma unroll 2
  for (int ks = 0; ks < 8; ++ks) {
    s16x8 bf[4], af[2];
#pragma unroll
    for (int nf = 0; nf < 4; ++nf)
      bf[nf] = *(const s16x8*)(wrow + (size_t)(wv * 4 + nf) * 4096 + ks * 512);
#pragma unroll
    for (int mf = 0; mf < 2; ++mf) {
      int row = mf * 16 + lr;
      int grp = ks * 4 + lk;
      int qr = (row >> 3) & 3;
      af[mf] = *(const s16x8*)(hb + row * 132 + ((grp ^ qr) << 2));
    }
#pragma unroll
    for (int mf = 0; mf < 2; ++mf)
#pragma unroll
      for (int nf = 0; nf < 4; ++nf)
        acc[mf][nf] = __builtin_amdgcn_mfma_f32_16x16x32_bf16(
            af[mf], bf[nf], acc[mf][nf], 0, 0, 0);
  }

  // epilogue: BN + GLU (packed col j pairs with j+32 -> frag nf vs nf+2, same lane)
  int cb = wv * 32;
#pragma unroll
  for (int nf = 0; nf < 2; ++nf) {
    float4 bn = bnp[cb + nf * 16 + lr];
    int c = cb + nf * 16 + lr;
#pragma unroll
    for (int mf = 0; mf < 2; ++mf) {
#pragma unroll
      for (int r = 0; r < 4; ++r) {
        float a = acc[mf][nf][r], g = acc[mf][nf + 2][r];
        float av = fmaf(a, bn.x, bn.y);
        float gv = fmaf(g, bn.z, bn.w);
        float fv = av * fsig(gv);
        int t = t0 + mf * 16 + lk * 4 + r;
        featT[((size_t)b * TN + t) * 256 + c] = __float2bfloat16(fv);
      }
    }
  }
}

// ========== K2 v2 (reverted R14 config): 128-t tiles, 512 thr = 8 waves ==========
__global__ __launch_bounds__(512) void k2_pred(
    const float* __restrict__ xx,
    const float* __restrict__ wp0T, const float2* __restrict__ bnp0,
    const short* __restrict__ wp1M, const float2* __restrict__ bnp1,
    const short* __restrict__ wp2M, const float* __restrict__ p2_b,
    const float* __restrict__ norm_mean,
    float* __restrict__ wts, float* __restrict__ mvr) {
  int t0 = blockIdx.x * 128;
  int b = blockIdx.y;
  __shared__ float xin[2][192];     // t = t0-29+q, valid q<186
  __shared__ short h0T[160 * 40];
  __shared__ short h1T[144 * 40];
  int tid = threadIdx.x;
  for (int q = tid; q < 192; q += 512) {
    int t = t0 - 29 + q;
    float v = (q < 186 && t >= 0 && t < TN) ? xx[b * TN + t] : 0.f;
    xin[0][q] = v;
    xin[1][q] = v * v;
  }
  __syncthreads();
  {  // p0: K=31, 2 in-ch, f32 VALU; thread (ch, tq) -> 12 outputs
    int ch = tid & 31, tq = tid >> 5;    // tq 0..15
    int i0 = tq * 12;
    if (i0 < 156) {
      float2 bb0 = bnp0[ch];
      float a0[12];
#pragma unroll
      for (int j = 0; j < 12; ++j) a0[j] = 0.f;
#pragma unroll
      for (int ic = 0; ic < 2; ++ic) {
        float rr[44];
#pragma unroll
        for (int q = 0; q < 11; ++q) {
          float4 t4 = *(const float4*)(&xin[ic][i0 + q * 4]);
          rr[q * 4 + 0] = t4.x; rr[q * 4 + 1] = t4.y;
          rr[q * 4 + 2] = t4.z; rr[q * 4 + 3] = t4.w;
        }
#pragma unroll
        for (int k = 0; k < 31; ++k) {
          float w = wp0T[(ic * 31 + k) * 32 + ch];
#pragma unroll
          for (int j = 0; j < 12; ++j) a0[j] = fmaf(w, rr[j + k], a0[j]);
        }
      }
#pragma unroll
      for (int j = 0; j < 12; ++j) {
        int i = i0 + j;
        if (i < 156) {
          float v = a0[j] * bb0.x + bb0.y;
          float h = v * fsig(v);
          __hip_bfloat16 hv = __float2bfloat16(h);
          h0T[i * 40 + ch] = *(short*)&hv;
        }
      }
    }
    if (tid < 128) h0T[(156 + (tid >> 5)) * 40 + (tid & 31)] = 0;  // zero pad rows
  }
  __syncthreads();
  int l = tid & 63, wv = tid >> 6;
  int lrow = l & 15, lk8 = (l >> 4) * 8;
  {  // p1: 15 shifted MFMAs (K=32=ic); 9 m-frags over 8 waves (wave0 gets 2)
    f32x4 acc[2][2];
#pragma unroll
    for (int i = 0; i < 2; ++i)
#pragma unroll
      for (int j = 0; j < 2; ++j) acc[i][j] = (f32x4){0.f, 0.f, 0.f, 0.f};
    int nmf = (wv == 0) ? 2 : 1;
    for (int koff = 0; koff < 15; ++koff) {
      const short* bp = wp1M + koff * 1024;
      s16x8 bf0 = *(const s16x8*)(bp + l * 8);
      s16x8 bf1 = *(const s16x8*)(bp + 512 + l * 8);
      for (int mi = 0; mi < nmf; ++mi) {
        int mf = (mi == 0) ? wv : 8;
        s16x8 af = *(const s16x8*)(&h0T[(mf * 16 + koff + lrow) * 40 + lk8]);
        acc[mi][0] = __builtin_amdgcn_mfma_f32_16x16x32_bf16(af, bf0, acc[mi][0], 0, 0, 0);
        acc[mi][1] = __builtin_amdgcn_mfma_f32_16x16x32_bf16(af, bf1, acc[mi][1], 0, 0, 0);
      }
    }
    for (int mi = 0; mi < nmf; ++mi) {
      int mf = (mi == 0) ? wv : 8;
#pragma unroll
      for (int nf = 0; nf < 2; ++nf) {
        int ch = nf * 16 + lrow;
        float2 bb = bnp1[ch];
#pragma unroll
        for (int r = 0; r < 4; ++r) {
          int row = mf * 16 + (l >> 4) * 4 + r;
          float v = acc[mi][nf][r] * bb.x + bb.y;
          float h = v * fsig(v);
          __hip_bfloat16 hv = __float2bfloat16(h);
          h1T[row * 40 + ch] = *(short*)&hv;
        }
      }
    }
  }
  __syncthreads();
  {  // p2: 15 shifted MFMAs, N=16 (2 cols used); 8 m-frags = 1/wave
    f32x4 acc2 = (f32x4){0.f, 0.f, 0.f, 0.f};
    for (int koff = 0; koff < 15; ++koff) {
      s16x8 bf = *(const s16x8*)(wp2M + koff * 512 + l * 8);
      s16x8 af = *(const s16x8*)(&h1T[(wv * 16 + koff + lrow) * 40 + lk8]);
      acc2 = __builtin_amdgcn_mfma_f32_16x16x32_bf16(af, bf, acc2, 0, 0, 0);
    }
    int ch = lrow;
    if (ch < 2) {
      float pb = p2_b[ch];
      float nm = norm_mean[0];
#pragma unroll
      for (int r = 0; r < 4; ++r) {
        int t = t0 + wv * 16 + (l >> 4) * 4 + r;
        float a = acc2[r] + pb;
        float s = fsig(a);
        if (ch == 0) wts[b * TN + t] = s;
        else         mvr[b * TN + t] = s * nm;
      }
    }
  }
}

// ========== K3 v2: coalesced LDS bounce + per-wave shfl scan (3 barriers) ==========
__global__ __launch_bounds__(256) void k3_scan(const float* __restrict__ mvr,
                                               float* __restrict__ poses,
                                               int* __restrict__ firstT) {
  int b = blockIdx.x, tid = threadIdx.x;
  __shared__ float stage[4096];
  __shared__ float wsum[4];
  __shared__ int shlast;
  for (int i = tid; i < 4096; i += 256) stage[i] = mvr[b * TN + i];  // coalesced
  __syncthreads();
  float v[16];
  float run = 0.f;
#pragma unroll
  for (int j = 0; j < 16; ++j) { run += stage[tid * 16 + j]; v[j] = run; }
  int l = tid & 63, wv = tid >> 6;
  float s = run;
#pragma unroll
  for (int off = 1; off < 64; off <<= 1) {   // wave inclusive scan
    float t = __shfl_up(s, off);
    if (l >= off) s += t;
  }
  if (l == 63) wsum[wv] = s;
  __syncthreads();
  float wpre = 0.f;
  for (int w2 = 0; w2 < wv; ++w2) wpre += wsum[w2];
  float incl = wpre + s;
  float total = wsum[0] + wsum[1] + wsum[2] + wsum[3];
  float excl = incl - run;
  float rn = total * (1.0f / 4096.0f);
  float inv = (rn > 1.0f) ? 1.0f / rn : 1.0f;
  float p16[16];
  float* pd = poses + b * TN + tid * 16;
#pragma unroll
  for (int j = 0; j < 16; ++j) { p16[j] = (excl + v[j]) * inv; pd[j] = p16[j]; }
  stage[tid] = p16[15];                      // boundary pose (bit-exact w/ stored)
  __syncthreads();
  int* ft = firstT + b * FTS;
  int prevf = (tid == 0) ? -1 : min((int)floorf(stage[tid - 1]), 4220);
  int f = prevf;
#pragma unroll
  for (int j = 0; j < 16; ++j) {
    f = min((int)floorf(p16[j]), 4220);
    for (int li = prevf + 1; li <= f; ++li) ft[li] = tid * 16 + j;
    prevf = f;
  }
  if (tid == 255) shlast = f;
  __syncthreads();
  for (int li = shlast + 1 + tid; li < FTS; li += 256) ft[li] = TN;
}

// ========== K4: gather pool v3 — register running-sums, 16-row tiles ==========
__global__ __launch_bounds__(256) void k4_gather(
    const __hip_bfloat16* __restrict__ featT, const float* __restrict__ wts,
    const float* __restrict__ poses, const int* __restrict__ firstT,
    float* __restrict__ out) {
  int d = blockIdx.x + 257 * blockIdx.y;         // 0..4111
  int w = (d & 7) * 514 + (d >> 3);              // XCD k owns b in [2k,2k+2), all lx
  int lx = w % 257, b = w / 257;
  int l0 = lx * 16;
  __shared__ float acc[16][259];
  int tid = threadIdx.x;
  for (int i = tid; i < 16 * 259; i += 256) ((float*)acc)[i] = 0.f;
  const int* ft = firstT + b * FTS;
  int ts = (l0 == 0) ? 0 : ft[l0 - 1];
  int te = ft[l0 + 16];
  __syncthreads();
  int c = tid;
  if (ts < te) {
    const float* pp = poses + b * TN;
    const float* wp = wts + b * TN;
    const __hip_bfloat16* fp = featT + (size_t)(b * TN) * 256 + c;
    float p_cur = pp[ts];
    float w_cur = wp[ts];
    float f_cur = __bfloat162float(fp[(size_t)ts * 256]);
    float S_lo = 0.f, S_hi = 0.f;
    int cur = (int)floorf(p_cur);
    for (int t = ts; t < te; ++t) {
      float p_nxt = 0.f, w_nxt = 0.f, f_nxt = 0.f;
      if (t + 1 < te) {                          // prefetch next iter
        p_nxt = pp[t + 1];
        w_nxt = wp[t + 1];
        f_nxt = __bfloat162float(fp[(size_t)(t + 1) * 256]);
      }
      int fi = (int)floorf(p_cur);
      if (fi < cur) fi = cur;                    // FP scan-boundary wobble guard
      if (fi != cur) {                           // wave-uniform advance
        int r = cur - l0;
        if (r >= 0 && r < 16) acc[r][c] = S_lo;  // row cur is final
        if (fi == cur + 1) {
          S_lo = S_hi;
        } else {                                 // jump (FP anomaly / init only)
          int r2 = cur + 1 - l0;
          if (r2 >= 0 && r2 < 16) acc[r2][c] = S_hi;
          S_lo = 0.f;
        }
        S_hi = 0.f;
        cur = fi;
      }
      float w2 = p_cur - (float)fi;
      float fw = f_cur * w_cur;
      S_lo = fmaf(1.f - w2, fw, S_lo);
      S_hi = fmaf(w2, fw, S_hi);
      p_cur = p_nxt; w_cur = w_nxt; f_cur = f_nxt;
    }
    int r = cur - l0;                            // final rows
    if (r >= 0 && r < 16) acc[r][c] = S_lo;
    int r2 = cur + 1 - l0;
    if (r2 >= 0 && r2 < 16) acc[r2][c] = S_hi;
  }
  __syncthreads();
  // dump: 16 consecutive lanes cover 16 l of one c-row -> coalesced 64B segments
  for (int i = tid; i < 4096; i += 256) {
    int c2 = i >> 4, r = i & 15;
    int l = l0 + r;
    if (l < LOUT) out[((size_t)b * 256 + c2) * LOUT + l] = acc[r][c2];
  }
}

// ======================= launch =======================
extern "C" void kernel_launch(void* const* d_in, const int* in_sizes, int n_in,
                              void* d_out, int out_size, void* d_ws, size_t ws_size,
                              hipStream_t stream) {
  const float* x       = (const float*)d_in[0];
  const float* conv1_w = (const float*)d_in[1];
  const float* bn1_g   = (const float*)d_in[2];
  const float* bn1_b   = (const float*)d_in[3];
  const float* bn1_m   = (const float*)d_in[4];
  const float* bn1_v   = (const float*)d_in[5];
  const float* w1x1    = (const float*)d_in[6];
  const float* p0_w    = (const float*)d_in[7];
  const float* p0_b    = (const float*)d_in[8];
  const float* p0g     = (const float*)d_in[9];
  const float* p0bb    = (const float*)d_in[10];
  const float* p0m     = (const float*)d_in[11];
  const float* p0v     = (const float*)d_in[12];
  const float* p1_w    = (const float*)d_in[13];
  const float* p1_b    = (const float*)d_in[14];
  const float* p1g     = (const float*)d_in[15];
  const float* p1bb    = (const float*)d_in[16];
  const float* p1m     = (const float*)d_in[17];
  const float* p1v     = (const float*)d_in[18];
  const float* p2_w    = (const float*)d_in[19];
  const float* p2_b    = (const float*)d_in[20];
  const float* nmean   = (const float*)d_in[21];

  char* ws = (char*)d_ws;
  __hip_bfloat16* featT = (__hip_bfloat16*)ws;
  short* wBpk   = (short*)(ws + 33554432);
  float4* bnp   = (float4*)(ws + 33816576);
  float* wp0T   = (float*)(ws + 33820672);
  short* wp1M   = (short*)(ws + 33828864);
  short* wp2M   = (short*)(ws + 33859584);
  float2* bnp0  = (float2*)(ws + 33874944);
  float2* bnp1  = (float2*)(ws + 33875200);
  float* xx     = (float*)(ws + 33890304);
  float* wts    = (float*)(ws + 34152448);
  float* mvr    = (float*)(ws + 34414592);
  float* poses  = (float*)(ws + 34676736);
  int*   firstT = (int*)  (ws + 34938880);
  float* out    = (float*)d_out;

  k0_prep<<<dim3(572), dim3(256), 0, stream>>>(
      conv1_w, p0_w, p1_w, p2_w, bn1_g, bn1_b, bn1_m, bn1_v,
      p0_b, p0g, p0bb, p0m, p0v, p1_b, p1g, p1bb, p1m, p1v,
      wBpk, bnp, wp0T, wp1M, wp2M, bnp0, bnp1);
  k1_mfma<<<dim3(128, 16), dim3(512), 0, stream>>>(x, w1x1, wBpk, bnp, featT, xx);
  k2_pred<<<dim3(32, 16), dim3(512), 0, stream>>>(xx, wp0T, bnp0, wp1M, bnp1,
                                                  wp2M, p2_b, nmean, wts, mvr);
  k3_scan<<<dim3(16), dim3(256), 0, stream>>>(mvr, poses, firstT);
  k4_gather<<<dim3(257, 16), dim3(256), 0, stream>>>(featT, wts, poses, firstT, out);
}

// Round 17
// 90.079 us; speedup vs baseline: 1.1063x; 1.0352x over previous
//
#include <hip/hip_runtime.h>
#include <hip/hip_bf16.h>

#define BB   16
#define CIN  256
#define TN   4096
#define LOUT 4110
#define FTS  4224   // first_t per-batch stride (ints)

typedef __attribute__((ext_vector_type(8))) short s16x8;
typedef __attribute__((ext_vector_type(4))) float f32x4;

__device__ __forceinline__ float fsig(float g) {   // sigmoid w/ HW rcp (1 ulp)
  return __builtin_amdgcn_rcpf(1.f + __expf(-g));
}

// ---------------- workspace layout (bytes) ----------------
// featT  bf16 [B][T][256]        0          (33554432)
// wBpk   bf16 fragment-packed    33554432   (262144)  -> 33816576
// bnp    float4[256]             33816576   (4096)    -> 33820672
// wp0T   f32  [62][32]           33820672   (8192)    -> 33828864
// wp1M   bf16 frag-packed p1     33828864   (30720)   -> 33859584
// wp2M   bf16 frag-packed p2     33859584   (15360)   -> 33874944
// bnp0   float2[32]              33874944   (256)     -> 33875200
// bnp1   float2[32]              33875200   (256)     -> 33875456
// xx     f32  [B][T]             33890304
// wts    f32  [B][T]             34152448
// mvr    f32  [B][T]             34414592
// poses  f32  [B][T]             34676736
// firstT int  [B][4224]          34938880   (end 35209216)

// ======================= K0: weight prep =======================
__global__ __launch_bounds__(256) void k0_prep(
    const float* __restrict__ conv1_w, const float* __restrict__ p0_w,
    const float* __restrict__ p1_w, const float* __restrict__ p2_w,
    const float* __restrict__ bn1_g, const float* __restrict__ bn1_b,
    const float* __restrict__ bn1_m, const float* __restrict__ bn1_v,
    const float* __restrict__ p0_b, const float* __restrict__ p0g,
    const float* __restrict__ p0bb, const float* __restrict__ p0m,
    const float* __restrict__ p0v,
    const float* __restrict__ p1_b, const float* __restrict__ p1g,
    const float* __restrict__ p1bb, const float* __restrict__ p1m,
    const float* __restrict__ p1v,
    short* __restrict__ wBpk, float4* __restrict__ bnp,
    float* __restrict__ wp0T, short* __restrict__ wp1M,
    short* __restrict__ wp2M, float2* __restrict__ bnp0,
    float2* __restrict__ bnp1) {
  int bid = blockIdx.x, tid = threadIdx.x;
  if (bid < 512) {
    // wBpk flat: ((n16*8 + ks)*64 + l)*8 + i ; value = Wpacked[n16*16+(l&15)][ks*32+(l>>4)*8+i]
    int e = bid * 256 + tid;               // 0..131071
    int i = e & 7, l = (e >> 3) & 63, ks = (e >> 9) & 7, n16 = e >> 12;
    int n = n16 * 16 + (l & 15);           // packed col 0..511
    int j = n & 63;
    int co = (j < 32) ? ((n >> 6) * 32 + j) : (256 + (n >> 6) * 32 + (j - 32));
    int ci = ks * 32 + (l >> 4) * 8 + i;
    __hip_bfloat16 hv = __float2bfloat16(conv1_w[co * 256 + ci]);
    wBpk[e] = *(short*)&hv;
  } else {
    int idx = (bid - 512) * 256 + tid;     // 0..15359
    if (idx < 1984) {
      int ch = idx & 31, rem = idx >> 5;
      int ic = rem / 31, k = rem % 31;
      wp0T[idx] = p0_w[(ch * 2 + ic) * 31 + k];
    }
    {  // wp1M: idx bits [0:3)=i, [3:9)=l, [9)=nf, [10:..)=koff
      int i = idx & 7, l = (idx >> 3) & 63, nf = (idx >> 9) & 1, koff = idx >> 10;
      int ch = nf * 16 + (l & 15), ic = (l >> 4) * 8 + i;
      __hip_bfloat16 hv = __float2bfloat16(p1_w[(ch * 32 + ic) * 15 + koff]);
      wp1M[idx] = *(short*)&hv;
    }
    if (idx < 7680) {  // wp2M: bits [0:3)=i, [3:9)=l, [9:..)=koff
      int i = idx & 7, l = (idx >> 3) & 63, koff = idx >> 9;
      int n = l & 15, ic = (l >> 4) * 8 + i;
      float v = (n < 2) ? p2_w[(n * 32 + ic) * 15 + koff] : 0.f;
      __hip_bfloat16 hv = __float2bfloat16(v);
      wp2M[idx] = *(short*)&hv;
    }
    if (idx < 32) {
      int ch = idx;
      float sc = p0g[ch] * rsqrtf(p0v[ch] + 1e-5f);
      bnp0[ch] = make_float2(sc, (p0_b[ch] - p0m[ch]) * sc + p0bb[ch]);
    }
    if (idx >= 32 && idx < 64) {
      int ch = idx - 32;
      float sc = p1g[ch] * rsqrtf(p1v[ch] + 1e-5f);
      bnp1[ch] = make_float2(sc, (p1_b[ch] - p1m[ch]) * sc + p1bb[ch]);
    }
    if (idx < 256) {
      int c = idx;
      float sa = bn1_g[c] * rsqrtf(bn1_v[c] + 1e-3f);
      float ba = bn1_b[c] - bn1_m[c] * sa;
      float sg = bn1_g[c + 256] * rsqrtf(bn1_v[c + 256] + 1e-3f);
      float bg = bn1_b[c + 256] - bn1_m[c + 256] * sg;
      bnp[c] = make_float4(sa, ba, sg, bg);
    }
  }
}

// ========== K1 v9 (R14 best): single-barrier full-N block + fused staging ==========
// grid (64 ty, 16 b), 512 thr = 8 waves. Block: 64t x 512n x 256k.
// Staging: thread (j=tid>>4, tc=tid&15), 4 iters; cvt f32->bf16 ONCE; LDS
// hb[64][132] u32 bf16-pairs, XOR swizzle C ^ ((tc>>1)&3)<<2 (write 2-way free,
// read = measured-OK). xx in same pass. ONE barrier, then per wave:
// 4m x 4n x 8ks = 128 consecutive MFMAs (A: LDS b128, B: L2-resident wBpk).
__global__ __launch_bounds__(512, 4) void k1_mfma(
    const float* __restrict__ x, const float* __restrict__ w1x1,
    const short* __restrict__ wBpk, const float4* __restrict__ bnp,
    __hip_bfloat16* __restrict__ featT, float* __restrict__ xx) {
  int ty = blockIdx.x, b = blockIdx.y;
  int t0 = ty * 64;
  __shared__ __align__(16) unsigned int hb[64 * 132];
  __shared__ float xws[8][68];
  int tid = threadIdx.x;
  int l = tid & 63, wv = tid >> 6;
  int j = tid >> 4;                      // 0..31 (block-wide cpair sub)
  int tc = tid & 15;
  int q = (tc >> 1) & 3;
  const float* xb = x + (size_t)b * (CIN * TN) + t0 + 4 * tc;
  float xxp[4] = {0.f, 0.f, 0.f, 0.f};
#pragma unroll
  for (int iter = 0; iter < 4; ++iter) {
    int C = j + 32 * iter;               // cpair 0..127
    int ci = 2 * C;
    float4 f0 = *(const float4*)(xb + (size_t)ci * TN);
    float4 f1 = *(const float4*)(xb + (size_t)(ci + 1) * TN);
    float w0 = w1x1[ci], w1 = w1x1[ci + 1];
    unsigned int* dst = hb + (C ^ (q << 2));
    float fa[4] = {f0.x, f0.y, f0.z, f0.w};
    float fb[4] = {f1.x, f1.y, f1.z, f1.w};
#pragma unroll
    for (int r = 0; r < 4; ++r) {
      __hip_bfloat16 lo = __float2bfloat16(fa[r]);
      __hip_bfloat16 hi = __float2bfloat16(fb[r]);
      unsigned int pk = (unsigned int)(*(unsigned short*)&lo) |
                        ((unsigned int)(*(unsigned short*)&hi) << 16);
      dst[(4 * tc + r) * 132] = pk;
      xxp[r] = fmaf(w0, fa[r], fmaf(w1, fb[r], xxp[r]));
    }
  }
#pragma unroll
  for (int r = 0; r < 4; ++r) {          // reduce over same-tc lanes (stride 16)
    xxp[r] += __shfl_xor(xxp[r], 16);
    xxp[r] += __shfl_xor(xxp[r], 32);
  }
  if (l < 16) {
#pragma unroll
    for (int r = 0; r < 4; ++r) xws[wv][4 * l + r] = xxp[r];
  }
  __syncthreads();                       // hb + xws ready
  if (tid < 64)
    xx[b * TN + t0 + tid] = ((xws[0][tid] + xws[1][tid]) + (xws[2][tid] + xws[3][tid])) +
                            ((xws[4][tid] + xws[5][tid]) + (xws[6][tid] + xws[7][tid]));

  int lr = l & 15, lk = l >> 4;
  const short* wrow = wBpk + (size_t)l * 8;
  f32x4 acc[4][4];
#pragma unroll
  for (int i = 0; i < 4; ++i)
#pragma unroll
    for (int n = 0; n < 4; ++n) acc[i][n] = (f32x4){0.f, 0.f, 0.f, 0.f};

#pragma unroll 2
  for (int ks = 0; ks < 8; ++ks) {
    s16x8 bf[4], af[4];
#pragma unroll
    for (int nf = 0; nf < 4; ++nf)
      bf[nf] = *(const s16x8*)(wrow + (size_t)(wv * 4 + nf) * 4096 + ks * 512);
#pragma unroll
    for (int mf = 0; mf < 4; ++mf) {
      int row = mf * 16 + lr;
      int grp = ks * 4 + lk;
      int qr = (row >> 3) & 3;
      af[mf] = *(const s16x8*)(hb + row * 132 + ((grp ^ qr) << 2));
    }
#pragma unroll
    for (int mf = 0; mf < 4; ++mf)
#pragma unroll
      for (int nf = 0; nf < 4; ++nf)
        acc[mf][nf] = __builtin_amdgcn_mfma_f32_16x16x32_bf16(
            af[mf], bf[nf], acc[mf][nf], 0, 0, 0);
  }

  // epilogue: BN + GLU (packed col j pairs with j+32 -> frag nf vs nf+2, same lane)
  int cb = wv * 32;
#pragma unroll
  for (int nf = 0; nf < 2; ++nf) {
    float4 bn = bnp[cb + nf * 16 + lr];
    int c = cb + nf * 16 + lr;
#pragma unroll
    for (int mf = 0; mf < 4; ++mf) {
#pragma unroll
      for (int r = 0; r < 4; ++r) {
        float a = acc[mf][nf][r], g = acc[mf][nf + 2][r];
        float av = fmaf(a, bn.x, bn.y);
        float gv = fmaf(g, bn.z, bn.w);
        float fv = av * fsig(gv);
        int t = t0 + mf * 16 + lk * 4 + r;
        featT[((size_t)b * TN + t) * 256 + c] = __float2bfloat16(fv);
      }
    }
  }
}

// ========== K2 v2 (R14 config): 128-t tiles, 512 thr = 8 waves ==========
__global__ __launch_bounds__(512) void k2_pred(
    const float* __restrict__ xx,
    const float* __restrict__ wp0T, const float2* __restrict__ bnp0,
    const short* __restrict__ wp1M, const float2* __restrict__ bnp1,
    const short* __restrict__ wp2M, const float* __restrict__ p2_b,
    const float* __restrict__ norm_mean,
    float* __restrict__ wts, float* __restrict__ mvr) {
  int t0 = blockIdx.x * 128;
  int b = blockIdx.y;
  __shared__ float xin[2][192];     // t = t0-29+q, valid q<186
  __shared__ short h0T[160 * 40];
  __shared__ short h1T[144 * 40];
  int tid = threadIdx.x;
  for (int q = tid; q < 192; q += 512) {
    int t = t0 - 29 + q;
    float v = (q < 186 && t >= 0 && t < TN) ? xx[b * TN + t] : 0.f;
    xin[0][q] = v;
    xin[1][q] = v * v;
  }
  __syncthreads();
  {  // p0: K=31, 2 in-ch, f32 VALU; thread (ch, tq) -> 12 outputs
    int ch = tid & 31, tq = tid >> 5;    // tq 0..15
    int i0 = tq * 12;
    if (i0 < 156) {
      float2 bb0 = bnp0[ch];
      float a0[12];
#pragma unroll
      for (int j = 0; j < 12; ++j) a0[j] = 0.f;
#pragma unroll
      for (int ic = 0; ic < 2; ++ic) {
        float rr[44];
#pragma unroll
        for (int q = 0; q < 11; ++q) {
          float4 t4 = *(const float4*)(&xin[ic][i0 + q * 4]);
          rr[q * 4 + 0] = t4.x; rr[q * 4 + 1] = t4.y;
          rr[q * 4 + 2] = t4.z; rr[q * 4 + 3] = t4.w;
        }
#pragma unroll
        for (int k = 0; k < 31; ++k) {
          float w = wp0T[(ic * 31 + k) * 32 + ch];
#pragma unroll
          for (int j = 0; j < 12; ++j) a0[j] = fmaf(w, rr[j + k], a0[j]);
        }
      }
#pragma unroll
      for (int j = 0; j < 12; ++j) {
        int i = i0 + j;
        if (i < 156) {
          float v = a0[j] * bb0.x + bb0.y;
          float h = v * fsig(v);
          __hip_bfloat16 hv = __float2bfloat16(h);
          h0T[i * 40 + ch] = *(short*)&hv;
        }
      }
    }
    if (tid < 128) h0T[(156 + (tid >> 5)) * 40 + (tid & 31)] = 0;  // zero pad rows
  }
  __syncthreads();
  int l = tid & 63, wv = tid >> 6;
  int lrow = l & 15, lk8 = (l >> 4) * 8;
  {  // p1: 15 shifted MFMAs (K=32=ic); 9 m-frags over 8 waves (wave0 gets 2)
    f32x4 acc[2][2];
#pragma unroll
    for (int i = 0; i < 2; ++i)
#pragma unroll
      for (int j = 0; j < 2; ++j) acc[i][j] = (f32x4){0.f, 0.f, 0.f, 0.f};
    int nmf = (wv == 0) ? 2 : 1;
    for (int koff = 0; koff < 15; ++koff) {
      const short* bp = wp1M + koff * 1024;
      s16x8 bf0 = *(const s16x8*)(bp + l * 8);
      s16x8 bf1 = *(const s16x8*)(bp + 512 + l * 8);
      for (int mi = 0; mi < nmf; ++mi) {
        int mf = (mi == 0) ? wv : 8;
        s16x8 af = *(const s16x8*)(&h0T[(mf * 16 + koff + lrow) * 40 + lk8]);
        acc[mi][0] = __builtin_amdgcn_mfma_f32_16x16x32_bf16(af, bf0, acc[mi][0], 0, 0, 0);
        acc[mi][1] = __builtin_amdgcn_mfma_f32_16x16x32_bf16(af, bf1, acc[mi][1], 0, 0, 0);
      }
    }
    for (int mi = 0; mi < nmf; ++mi) {
      int mf = (mi == 0) ? wv : 8;
#pragma unroll
      for (int nf = 0; nf < 2; ++nf) {
        int ch = nf * 16 + lrow;
        float2 bb = bnp1[ch];
#pragma unroll
        for (int r = 0; r < 4; ++r) {
          int row = mf * 16 + (l >> 4) * 4 + r;
          float v = acc[mi][nf][r] * bb.x + bb.y;
          float h = v * fsig(v);
          __hip_bfloat16 hv = __float2bfloat16(h);
          h1T[row * 40 + ch] = *(short*)&hv;
        }
      }
    }
  }
  __syncthreads();
  {  // p2: 15 shifted MFMAs, N=16 (2 cols used); 8 m-frags = 1/wave
    f32x4 acc2 = (f32x4){0.f, 0.f, 0.f, 0.f};
    for (int koff = 0; koff < 15; ++koff) {
      s16x8 bf = *(const s16x8*)(wp2M + koff * 512 + l * 8);
      s16x8 af = *(const s16x8*)(&h1T[(wv * 16 + koff + lrow) * 40 + lk8]);
      acc2 = __builtin_amdgcn_mfma_f32_16x16x32_bf16(af, bf, acc2, 0, 0, 0);
    }
    int ch = lrow;
    if (ch < 2) {
      float pb = p2_b[ch];
      float nm = norm_mean[0];
#pragma unroll
      for (int r = 0; r < 4; ++r) {
        int t = t0 + wv * 16 + (l >> 4) * 4 + r;
        float a = acc2[r] + pb;
        float s = fsig(a);
        if (ch == 0) wts[b * TN + t] = s;
        else         mvr[b * TN + t] = s * nm;
      }
    }
  }
}

// ========== K3 v2: coalesced LDS bounce + per-wave shfl scan (3 barriers) ==========
__global__ __launch_bounds__(256) void k3_scan(const float* __restrict__ mvr,
                                               float* __restrict__ poses,
                                               int* __restrict__ firstT) {
  int b = blockIdx.x, tid = threadIdx.x;
  __shared__ float stage[4096];
  __shared__ float wsum[4];
  __shared__ int shlast;
  for (int i = tid; i < 4096; i += 256) stage[i] = mvr[b * TN + i];  // coalesced
  __syncthreads();
  float v[16];
  float run = 0.f;
#pragma unroll
  for (int j = 0; j < 16; ++j) { run += stage[tid * 16 + j]; v[j] = run; }
  int l = tid & 63, wv = tid >> 6;
  float s = run;
#pragma unroll
  for (int off = 1; off < 64; off <<= 1) {   // wave inclusive scan
    float t = __shfl_up(s, off);
    if (l >= off) s += t;
  }
  if (l == 63) wsum[wv] = s;
  __syncthreads();
  float wpre = 0.f;
  for (int w2 = 0; w2 < wv; ++w2) wpre += wsum[w2];
  float incl = wpre + s;
  float total = wsum[0] + wsum[1] + wsum[2] + wsum[3];
  float excl = incl - run;
  float rn = total * (1.0f / 4096.0f);
  float inv = (rn > 1.0f) ? 1.0f / rn : 1.0f;
  float p16[16];
  float* pd = poses + b * TN + tid * 16;
#pragma unroll
  for (int j = 0; j < 16; ++j) { p16[j] = (excl + v[j]) * inv; pd[j] = p16[j]; }
  stage[tid] = p16[15];                      // boundary pose (bit-exact w/ stored)
  __syncthreads();
  int* ft = firstT + b * FTS;
  int prevf = (tid == 0) ? -1 : min((int)floorf(stage[tid - 1]), 4220);
  int f = prevf;
#pragma unroll
  for (int j = 0; j < 16; ++j) {
    f = min((int)floorf(p16[j]), 4220);
    for (int li = prevf + 1; li <= f; ++li) ft[li] = tid * 16 + j;
    prevf = f;
  }
  if (tid == 255) shlast = f;
  __syncthreads();
  for (int li = shlast + 1 + tid; li < FTS; li += 256) ft[li] = TN;
}

// ========== K4: gather pool v3 — register running-sums, 16-row tiles ==========
__global__ __launch_bounds__(256) void k4_gather(
    const __hip_bfloat16* __restrict__ featT, const float* __restrict__ wts,
    const float* __restrict__ poses, const int* __restrict__ firstT,
    float* __restrict__ out) {
  int d = blockIdx.x + 257 * blockIdx.y;         // 0..4111
  int w = (d & 7) * 514 + (d >> 3);              // XCD k owns b in [2k,2k+2), all lx
  int lx = w % 257, b = w / 257;
  int l0 = lx * 16;
  __shared__ float acc[16][259];
  int tid = threadIdx.x;
  for (int i = tid; i < 16 * 259; i += 256) ((float*)acc)[i] = 0.f;
  const int* ft = firstT + b * FTS;
  int ts = (l0 == 0) ? 0 : ft[l0 - 1];
  int te = ft[l0 + 16];
  __syncthreads();
  int c = tid;
  if (ts < te) {
    const float* pp = poses + b * TN;
    const float* wp = wts + b * TN;
    const __hip_bfloat16* fp = featT + (size_t)(b * TN) * 256 + c;
    float p_cur = pp[ts];
    float w_cur = wp[ts];
    float f_cur = __bfloat162float(fp[(size_t)ts * 256]);
    float S_lo = 0.f, S_hi = 0.f;
    int cur = (int)floorf(p_cur);
    for (int t = ts; t < te; ++t) {
      float p_nxt = 0.f, w_nxt = 0.f, f_nxt = 0.f;
      if (t + 1 < te) {                          // prefetch next iter
        p_nxt = pp[t + 1];
        w_nxt = wp[t + 1];
        f_nxt = __bfloat162float(fp[(size_t)(t + 1) * 256]);
      }
      int fi = (int)floorf(p_cur);
      if (fi < cur) fi = cur;                    // FP scan-boundary wobble guard
      if (fi != cur) {                           // wave-uniform advance
        int r = cur - l0;
        if (r >= 0 && r < 16) acc[r][c] = S_lo;  // row cur is final
        if (fi == cur + 1) {
          S_lo = S_hi;
        } else {                                 // jump (FP anomaly / init only)
          int r2 = cur + 1 - l0;
          if (r2 >= 0 && r2 < 16) acc[r2][c] = S_hi;
          S_lo = 0.f;
        }
        S_hi = 0.f;
        cur = fi;
      }
      float w2 = p_cur - (float)fi;
      float fw = f_cur * w_cur;
      S_lo = fmaf(1.f - w2, fw, S_lo);
      S_hi = fmaf(w2, fw, S_hi);
      p_cur = p_nxt; w_cur = w_nxt; f_cur = f_nxt;
    }
    int r = cur - l0;                            // final rows
    if (r >= 0 && r < 16) acc[r][c] = S_lo;
    int r2 = cur + 1 - l0;
    if (r2 >= 0 && r2 < 16) acc[r2][c] = S_hi;
  }
  __syncthreads();
  // dump: 16 consecutive lanes cover 16 l of one c-row -> coalesced 64B segments
  for (int i = tid; i < 4096; i += 256) {
    int c2 = i >> 4, r = i & 15;
    int l = l0 + r;
    if (l < LOUT) out[((size_t)b * 256 + c2) * LOUT + l] = acc[r][c2];
  }
}

// ======================= launch =======================
extern "C" void kernel_launch(void* const* d_in, const int* in_sizes, int n_in,
                              void* d_out, int out_size, void* d_ws, size_t ws_size,
                              hipStream_t stream) {
  const float* x       = (const float*)d_in[0];
  const float* conv1_w = (const float*)d_in[1];
  const float* bn1_g   = (const float*)d_in[2];
  const float* bn1_b   = (const float*)d_in[3];
  const float* bn1_m   = (const float*)d_in[4];
  const float* bn1_v   = (const float*)d_in[5];
  const float* w1x1    = (const float*)d_in[6];
  const float* p0_w    = (const float*)d_in[7];
  const float* p0_b    = (const float*)d_in[8];
  const float* p0g     = (const float*)d_in[9];
  const float* p0bb    = (const float*)d_in[10];
  const float* p0m     = (const float*)d_in[11];
  const float* p0v     = (const float*)d_in[12];
  const float* p1_w    = (const float*)d_in[13];
  const float* p1_b    = (const float*)d_in[14];
  const float* p1g     = (const float*)d_in[15];
  const float* p1bb    = (const float*)d_in[16];
  const float* p1m     = (const float*)d_in[17];
  const float* p1v     = (const float*)d_in[18];
  const float* p2_w    = (const float*)d_in[19];
  const float* p2_b    = (const float*)d_in[20];
  const float* nmean   = (const float*)d_in[21];

  char* ws = (char*)d_ws;
  __hip_bfloat16* featT = (__hip_bfloat16*)ws;
  short* wBpk   = (short*)(ws + 33554432);
  float4* bnp   = (float4*)(ws + 33816576);
  float* wp0T   = (float*)(ws + 33820672);
  short* wp1M   = (short*)(ws + 33828864);
  short* wp2M   = (short*)(ws + 33859584);
  float2* bnp0  = (float2*)(ws + 33874944);
  float2* bnp1  = (float2*)(ws + 33875200);
  float* xx     = (float*)(ws + 33890304);
  float* wts    = (float*)(ws + 34152448);
  float* mvr    = (float*)(ws + 34414592);
  float* poses  = (float*)(ws + 34676736);
  int*   firstT = (int*)  (ws + 34938880);
  float* out    = (float*)d_out;

  k0_prep<<<dim3(572), dim3(256), 0, stream>>>(
      conv1_w, p0_w, p1_w, p2_w, bn1_g, bn1_b, bn1_m, bn1_v,
      p0_b, p0g, p0bb, p0m, p0v, p1_b, p1g, p1bb, p1m, p1v,
      wBpk, bnp, wp0T, wp1M, wp2M, bnp0, bnp1);
  k1_mfma<<<dim3(64, 16), dim3(512), 0, stream>>>(x, w1x1, wBpk, bnp, featT, xx);
  k2_pred<<<dim3(32, 16), dim3(512), 0, stream>>>(xx, wp0T, bnp0, wp1M, bnp1,
                                                  wp2M, p2_b, nmean, wts, mvr);
  k3_scan<<<dim3(16), dim3(256), 0, stream>>>(mvr, poses, firstT);
  k4_gather<<<dim3(257, 16), dim3(256), 0, stream>>>(featT, wts, poses, firstT, out);
}